// Round 1
// baseline (170.969 us; speedup 1.0000x reference)
//
#include <hip/hip_runtime.h>
#include <math.h>

#define BB 4
#define NN 1024
#define DIN 128
#define DOUT 64
#define SLOPE 0.01f

// Kernel 1: x12[b,n,0:64] = x[b,n,:] @ w1 ; x12[b,n,64:128] = x[b,n,:] @ w2
__global__ __launch_bounds__(128) void proj_kernel(
    const float* __restrict__ x, const float* __restrict__ w1,
    const float* __restrict__ w2, float* __restrict__ x12) {
  int bn = blockIdx.x;      // 0..B*N-1
  int t = threadIdx.x;      // 0..127
  __shared__ float xr[DIN];
  xr[t] = x[(size_t)bn * DIN + t];
  __syncthreads();
  const float* w = (t < DOUT) ? w1 : w2;
  int d = t & 63;
  float acc = 0.f;
#pragma unroll 8
  for (int k = 0; k < DIN; ++k) acc = fmaf(xr[k], w[k * DOUT + d], acc);
  x12[(size_t)bn * 128 + t] = acc;
}

// Kernel 2: one block per (b,i) destination row.
__global__ __launch_bounds__(256) void gat_row_kernel(
    const float* __restrict__ x, const float* __restrict__ A_shape,
    const float* __restrict__ a_vec, const float* __restrict__ lin_w,
    const float* __restrict__ x12, float* __restrict__ out) {
  int bi = blockIdx.x;      // b*N + i
  int b = bi >> 10;
  int t = threadIdx.x;

  __shared__ float x1r[DOUT];
  __shared__ float av[DOUT];
  __shared__ float evals[NN];
  __shared__ int eidx[NN];
  __shared__ int nnz_s;
  __shared__ float agg2[DIN];
  __shared__ float wsum[4];

  if (t < DOUT) {
    x1r[t] = x12[(size_t)bi * 128 + t];
    av[t] = a_vec[t];
  }
  if (t == 0) nnz_s = 0;
  __syncthreads();

  // Phase A: compact nonzero mask indices (mask is binary 0/1)
  const float* mask_row = A_shape + (size_t)bi * NN;
  for (int j = t; j < NN; j += 256) {
    if (mask_row[j] != 0.f) {
      int slot = atomicAdd(&nnz_s, 1);
      eidx[slot] = j;
    }
  }
  __syncthreads();
  int nz = nnz_s;

  // Phase B: one score per thread over the compacted list
  const float* x2b = x12 + (size_t)b * NN * 128 + DOUT;  // x2 part, row stride 128
  float local_sum = 0.f;
  for (int s = t; s < nz; s += 256) {
    int j = eidx[s];
    const float* x2r = x2b + (size_t)j * 128;
    float sc = 0.f;
#pragma unroll
    for (int d0 = 0; d0 < DOUT; d0 += 4) {
      float4 x2v = *reinterpret_cast<const float4*>(x2r + d0);
      float4 x1v = *reinterpret_cast<const float4*>(&x1r[d0]);
      float4 avv = *reinterpret_cast<const float4*>(&av[d0]);
      float z;
      z = x1v.x + x2v.x; sc = fmaf(z >= 0.f ? z : SLOPE * z, avv.x, sc);
      z = x1v.y + x2v.y; sc = fmaf(z >= 0.f ? z : SLOPE * z, avv.y, sc);
      z = x1v.z + x2v.z; sc = fmaf(z >= 0.f ? z : SLOPE * z, avv.z, sc);
      z = x1v.w + x2v.w; sc = fmaf(z >= 0.f ? z : SLOPE * z, avv.w, sc);
    }
    sc = tanhf(sc * 0.125f) * 8.f;
    float e = expf(sc);
    evals[s] = e;
    local_sum += e;
  }

  // Phase C: block-reduce the row sum
#pragma unroll
  for (int off = 32; off > 0; off >>= 1)
    local_sum += __shfl_down(local_sum, off, 64);
  if ((t & 63) == 0) wsum[t >> 6] = local_sum;
  __syncthreads();
  float inv = 1.f / (wsum[0] + wsum[1] + wsum[2] + wsum[3]);

  // Phase D: agg[k] = inv * sum_s evals[s] * x[b, eidx[s], k]
  int k = t & 127;
  int g = t >> 7;
  const float* xb = x + (size_t)b * NN * DIN;
  float acck = 0.f;
  for (int s = g; s < nz; s += 2) {
    acck = fmaf(evals[s], xb[(size_t)eidx[s] * DIN + k], acck);
  }
  if (g == 1) agg2[k] = acck;
  __syncthreads();
  if (g == 0) agg2[k] = (acck + agg2[k]) * inv;
  __syncthreads();

  // Phase E: out[b,i,d] = lrelu( sum_k agg[k] * lin_w[d,k] )
  if (t < DOUT) {
    const float* lw = lin_w + (size_t)t * DIN;
    float o = 0.f;
#pragma unroll
    for (int k2 = 0; k2 < DIN; k2 += 4) {
      float4 lv = *reinterpret_cast<const float4*>(lw + k2);
      o = fmaf(agg2[k2 + 0], lv.x, o);
      o = fmaf(agg2[k2 + 1], lv.y, o);
      o = fmaf(agg2[k2 + 2], lv.z, o);
      o = fmaf(agg2[k2 + 3], lv.w, o);
    }
    o = o >= 0.f ? o : SLOPE * o;
    out[(size_t)bi * DOUT + t] = o;
  }
}

extern "C" void kernel_launch(void* const* d_in, const int* in_sizes, int n_in,
                              void* d_out, int out_size, void* d_ws, size_t ws_size,
                              hipStream_t stream) {
  const float* x = (const float*)d_in[0];
  const float* A_shape = (const float*)d_in[1];
  const float* w1 = (const float*)d_in[2];
  const float* w2 = (const float*)d_in[3];
  const float* a = (const float*)d_in[4];
  const float* lin_w = (const float*)d_in[5];
  float* out = (float*)d_out;
  float* x12 = (float*)d_ws;  // B*N*128 floats = 2 MB scratch

  proj_kernel<<<BB * NN, 128, 0, stream>>>(x, w1, w2, x12);
  gat_row_kernel<<<BB * NN, 256, 0, stream>>>(x, A_shape, a, lin_w, x12, out);
}

// Round 2
// 112.600 us; speedup vs baseline: 1.5184x; 1.5184x over previous
//
#include <hip/hip_runtime.h>
#include <math.h>

#define BB 4
#define NN 1024
#define DIN 128
#define DOUT 64
#define SLOPE 0.01f

// Kernel 1: x12[b,n,0:64] = x[b,n,:] @ w1 ; x12[b,n,64:128] = x[b,n,:] @ w2
// 16 rows per block, 256 threads: d = t&127 (col, w1 if <64 else w2),
// rh = t>>7 selects rows rh*8..rh*8+7. 8 accumulators per thread -> 8 outputs
// amortize each w load, 8-deep FMA ILP.
__global__ __launch_bounds__(256) void proj_kernel(
    const float* __restrict__ x, const float* __restrict__ w1,
    const float* __restrict__ w2, float* __restrict__ x12) {
  int t = threadIdx.x;
  int row0 = blockIdx.x * 16;
  __shared__ float xl[16][DIN];  // 8 KB

  // stage 16 x-rows (2048 floats = 512 float4), coalesced
  const float4* xg = reinterpret_cast<const float4*>(x + (size_t)row0 * DIN);
  float4* xls = reinterpret_cast<float4*>(&xl[0][0]);
  xls[t] = xg[t];
  xls[t + 256] = xg[t + 256];
  __syncthreads();

  int d = t & 127;
  int rh = t >> 7;  // 0/1 -> rows [0,8) or [8,16)
  const float* w = (d < DOUT) ? w1 : w2;
  int dc = d & 63;

  float acc[8] = {0.f, 0.f, 0.f, 0.f, 0.f, 0.f, 0.f, 0.f};
#pragma unroll 4
  for (int k = 0; k < DIN; ++k) {
    float wv = w[k * DOUT + dc];  // coalesced 256B per wave, L1-hot
#pragma unroll
    for (int r = 0; r < 8; ++r)
      acc[r] = fmaf(xl[rh * 8 + r][k], wv, acc[r]);  // LDS broadcast
  }
#pragma unroll
  for (int r = 0; r < 8; ++r)
    x12[(size_t)(row0 + rh * 8 + r) * 128 + d] = acc[r];
}

__device__ __forceinline__ float fast_edge_exp(float sc) {
  // e = exp(8*tanh(sc/8)); tanh via exp, clamped so __expf stays finite
  float z = sc * 0.125f;
  z = fminf(10.f, fmaxf(-10.f, z));
  float u = __expf(2.f * z);
  float th = (u - 1.f) / (u + 1.f);
  return __expf(8.f * th);
}

// Kernel 2: one block of 256 per (b,i) destination row.
__global__ __launch_bounds__(256) void gat_row_kernel(
    const float* __restrict__ x, const float* __restrict__ A_shape,
    const float* __restrict__ a_vec, const float* __restrict__ lin_w,
    const float* __restrict__ x12, float* __restrict__ out) {
  int bi = blockIdx.x;  // b*N + i
  int b = bi >> 10;
  int t = threadIdx.x;
  int lane = t & 63;
  int wave = t >> 6;

  __shared__ __align__(16) float x1r[DOUT];
  __shared__ __align__(16) float av[DOUT];
  __shared__ float evals[NN];
  __shared__ int eidx[NN];
  __shared__ float part[8][DIN];  // 4 KB: phase-D partials
  __shared__ __align__(16) float agg2[DIN];
  __shared__ float ep[4][DOUT];   // 1 KB: phase-E partials
  __shared__ float wsum[4];
  __shared__ int nnz_s;

  if (t < DOUT) {
    x1r[t] = x12[(size_t)bi * 128 + t];
    av[t] = a_vec[t];
  }
  if (t == 0) nnz_s = 0;
  __syncthreads();

  // ---- Phase A: ballot-compact nonzero mask indices ----
  const float* mask_row = A_shape + (size_t)bi * NN;
#pragma unroll
  for (int c = 0; c < 4; ++c) {
    int j = c * 256 + t;
    bool pred = (mask_row[j] != 0.f);
    unsigned long long m = __ballot(pred);
    int prefix = __popcll(m & ((1ull << lane) - 1ull));
    int base = 0;
    if (lane == 0) base = atomicAdd(&nnz_s, __popcll(m));
    base = __shfl(base, 0, 64);
    if (pred) eidx[base + prefix] = j;
  }
  __syncthreads();
  int nz = nnz_s;

  // ---- Phase B: scores. 16 lanes per edge, 16 edges concurrent ----
  const float* x2b = x12 + (size_t)b * NN * 128 + DOUT;  // x2 half, stride 128
  int l16 = t & 15;
  int grp = t >> 4;
  float4 x1v = reinterpret_cast<const float4*>(x1r)[l16];
  float4 avv = reinterpret_cast<const float4*>(av)[l16];
  float lsum = 0.f;
  for (int s = grp; s < nz; s += 16) {
    int j = eidx[s];
    float4 x2v = *reinterpret_cast<const float4*>(x2b + (size_t)j * 128 + l16 * 4);
    float z, sc = 0.f;
    z = x1v.x + x2v.x; sc = fmaf(z >= 0.f ? z : SLOPE * z, avv.x, sc);
    z = x1v.y + x2v.y; sc = fmaf(z >= 0.f ? z : SLOPE * z, avv.y, sc);
    z = x1v.z + x2v.z; sc = fmaf(z >= 0.f ? z : SLOPE * z, avv.z, sc);
    z = x1v.w + x2v.w; sc = fmaf(z >= 0.f ? z : SLOPE * z, avv.w, sc);
    // reduce across the 16-lane group
    sc += __shfl_xor(sc, 8, 64);
    sc += __shfl_xor(sc, 4, 64);
    sc += __shfl_xor(sc, 2, 64);
    sc += __shfl_xor(sc, 1, 64);
    if (l16 == 0) {
      float e = fast_edge_exp(sc);
      evals[s] = e;
      lsum += e;
    }
  }

  // ---- Phase C: block rowsum (non-leaders hold 0) ----
#pragma unroll
  for (int off = 32; off > 0; off >>= 1)
    lsum += __shfl_down(lsum, off, 64);
  if (lane == 0) wsum[wave] = lsum;
  __syncthreads();
  float inv = 1.f / (wsum[0] + wsum[1] + wsum[2] + wsum[3]);

  // ---- Phase D: agg[k] = inv * sum_s evals[s]*x[b,eidx[s],k] ----
  // 8 groups x 32 lanes; each group loads one full x-row (float4/lane) per step
  int l32 = t & 31;
  int g = t >> 5;
  const float* xb = x + (size_t)b * NN * DIN;
  float4 acc = {0.f, 0.f, 0.f, 0.f};
  for (int s = g; s < nz; s += 8) {
    int j = eidx[s];
    float wv = evals[s];
    float4 xv = *reinterpret_cast<const float4*>(xb + (size_t)j * 128 + l32 * 4);
    acc.x = fmaf(wv, xv.x, acc.x);
    acc.y = fmaf(wv, xv.y, acc.y);
    acc.z = fmaf(wv, xv.z, acc.z);
    acc.w = fmaf(wv, xv.w, acc.w);
  }
  *reinterpret_cast<float4*>(&part[g][l32 * 4]) = acc;
  __syncthreads();
  if (t < DIN) {
    float sum = 0.f;
#pragma unroll
    for (int g2 = 0; g2 < 8; ++g2) sum += part[g2][t];
    agg2[t] = sum * inv;
  }
  __syncthreads();

  // ---- Phase E: out[d] = lrelu(sum_k agg2[k]*lin_w[d,k]), 4-way k-split ----
  int d = t & 63;
  int q = t >> 6;  // k-quarter
  const float* lw = lin_w + (size_t)d * DIN + q * 32;
  const float* ag = agg2 + q * 32;
  float o = 0.f;
#pragma unroll
  for (int k = 0; k < 32; k += 4) {
    float4 lv = *reinterpret_cast<const float4*>(lw + k);
    o = fmaf(ag[k + 0], lv.x, o);
    o = fmaf(ag[k + 1], lv.y, o);
    o = fmaf(ag[k + 2], lv.z, o);
    o = fmaf(ag[k + 3], lv.w, o);
  }
  ep[q][d] = o;
  __syncthreads();
  if (t < DOUT) {
    float oo = ep[0][t] + ep[1][t] + ep[2][t] + ep[3][t];
    oo = oo >= 0.f ? oo : SLOPE * oo;
    out[(size_t)bi * DOUT + t] = oo;
  }
}

extern "C" void kernel_launch(void* const* d_in, const int* in_sizes, int n_in,
                              void* d_out, int out_size, void* d_ws, size_t ws_size,
                              hipStream_t stream) {
  const float* x = (const float*)d_in[0];
  const float* A_shape = (const float*)d_in[1];
  const float* w1 = (const float*)d_in[2];
  const float* w2 = (const float*)d_in[3];
  const float* a = (const float*)d_in[4];
  const float* lin_w = (const float*)d_in[5];
  float* out = (float*)d_out;
  float* x12 = (float*)d_ws;  // B*N*128 floats = 2 MB scratch

  proj_kernel<<<BB * NN / 16, 256, 0, stream>>>(x, w1, w2, x12);
  gat_row_kernel<<<BB * NN, 256, 0, stream>>>(x, A_shape, a, lin_w, x12, out);
}